// Round 5
// baseline (239.119 us; speedup 1.0000x reference)
//
#include <hip/hip_runtime.h>
#include <math.h>

#define N    24
#define D    256
#define BLK  256
#define NB   4            // batches per block = waves per block
#define CTS  28           // costT row stride (floats), 16B-aligned
#define INFV 1e9f
#define PROBE_ITERS 128   // L-calibration loop length

__device__ __forceinline__ int readlane_i(int x, int l) {
    return __builtin_amdgcn_readlane(x, l);
}
__device__ __forceinline__ float readlane_f(float x, int l) {
    return __uint_as_float((unsigned)__builtin_amdgcn_readlane((int)__float_as_uint(x), l));
}

// unsigned-min reduce over lanes 0..31 (lanes 32..63 must hold large keys);
// result valid in lane 31. Pure DPP/VALU — no DS pipe.
__device__ __forceinline__ unsigned wave_min32(unsigned x) {
    unsigned t;
    t = (unsigned)__builtin_amdgcn_update_dpp((int)x, (int)x, 0xB1,  0xF, 0xF, false); x = t < x ? t : x; // quad_perm [1,0,3,2]
    t = (unsigned)__builtin_amdgcn_update_dpp((int)x, (int)x, 0x4E,  0xF, 0xF, false); x = t < x ? t : x; // quad_perm [2,3,0,1]
    t = (unsigned)__builtin_amdgcn_update_dpp((int)x, (int)x, 0x114, 0xF, 0xF, false); x = t < x ? t : x; // row_shr:4
    t = (unsigned)__builtin_amdgcn_update_dpp((int)x, (int)x, 0x118, 0xF, 0xF, false); x = t < x ? t : x; // row_shr:8  -> lane15 = row min
    t = (unsigned)__builtin_amdgcn_update_dpp((int)x, (int)x, 0x142, 0xF, 0xF, false); x = t < x ? t : x; // row_bcast:15 -> lane31 = min(0..31)
    return x;
}

// C[i0][lane-col] with wave-uniform i0 — scalar-branch select (best measured
// variant: R0=104 µs vs cndmask-tree 112, ds_read 108).
__device__ __forceinline__ float csel(const float* cq, int i0) {
    switch (i0) {
        case 0:  return cq[0];   case 1:  return cq[1];
        case 2:  return cq[2];   case 3:  return cq[3];
        case 4:  return cq[4];   case 5:  return cq[5];
        case 6:  return cq[6];   case 7:  return cq[7];
        case 8:  return cq[8];   case 9:  return cq[9];
        case 10: return cq[10];  case 11: return cq[11];
        case 12: return cq[12];  case 13: return cq[13];
        case 14: return cq[14];  case 15: return cq[15];
        case 16: return cq[16];  case 17: return cq[17];
        case 18: return cq[18];  case 19: return cq[19];
        case 20: return cq[20];  case 21: return cq[21];
        case 22: return cq[22];  default: return cq[23];
    }
}

__device__ __forceinline__ unsigned packkey(float x, int lane) {
    unsigned key = __float_as_uint(x);
    key ^= (unsigned)((int)key >> 31) | 0x80000000u;
    return (key & 0xFFFFFFC0u) | (unsigned)lane;
}

#define DOT4(a, b) ((a).x*(b).x + (a).y*(b).y + (a).z*(b).z + (a).w*(b).w)
#define LGKM0() __asm__ volatile("s_waitcnt lgkmcnt(0)" ::: "memory")

__global__ __launch_bounds__(BLK) void hungarian_fused(
    const float* __restrict__ slots,
    const float* __restrict__ prev,
    float* __restrict__ out, int B)
{
    __shared__ __align__(16) float costT[NB][N][CTS]; // [wave][col][row]
    __shared__ int winner[NB][N];                     // col claiming row r
    __shared__ int colw[NB][N];                       // col_ind[row]

    const int tid  = threadIdx.x;
    const int lane = tid & 63;
    const int wv   = tid >> 6;
    const int bw   = blockIdx.x * NB + wv;
    if (bw >= B) return;

    // ============ Phase A: per-wave cost GEMM straight from global =========
    const int rg = lane >> 3;       // prev rows 3rg..3rg+2
    const int cg = lane & 7;        // cur  rows 3cg..3cg+2
    const float4* pA = (const float4*)(prev  + (size_t)bw * N * D) + rg * 3 * (D / 4);
    const float4* pC = (const float4*)(slots + (size_t)bw * N * D) + cg * 3 * (D / 4);

    float s00=0,s01=0,s02=0,s10=0,s11=0,s12=0,s20=0,s21=0,s22=0;
    float pa0=0,pa1=0,pa2=0,pc0=0,pc1=0,pc2=0;
    #pragma unroll 2
    for (int k = 0; k < 64; ++k) {
        float4 a0 = pA[k], a1 = pA[64+k], a2 = pA[128+k];
        float4 b0 = pC[k], b1 = pC[64+k], b2 = pC[128+k];
        s00 += DOT4(a0,b0); s01 += DOT4(a0,b1); s02 += DOT4(a0,b2);
        s10 += DOT4(a1,b0); s11 += DOT4(a1,b1); s12 += DOT4(a1,b2);
        s20 += DOT4(a2,b0); s21 += DOT4(a2,b1); s22 += DOT4(a2,b2);
        pa0 += DOT4(a0,a0); pa1 += DOT4(a1,a1); pa2 += DOT4(a2,a2);
        pc0 += DOT4(b0,b0); pc1 += DOT4(b1,b1); pc2 += DOT4(b2,b2);
    }
    float ira0 = 1.0f / fmaxf(sqrtf(pa0), 1e-12f);
    float ira1 = 1.0f / fmaxf(sqrtf(pa1), 1e-12f);
    float ira2 = 1.0f / fmaxf(sqrtf(pa2), 1e-12f);
    float irc0 = 1.0f / fmaxf(sqrtf(pc0), 1e-12f);
    float irc1 = 1.0f / fmaxf(sqrtf(pc1), 1e-12f);
    float irc2 = 1.0f / fmaxf(sqrtf(pc2), 1e-12f);

    {   // costT[col][row] = 1 - <prev_row, cur_col> * ira * irc
        float* ct = &costT[wv][0][0];
        const int cb = cg * 3, rb = rg * 3;
        ct[(cb+0)*CTS + rb+0] = 1.0f - s00*ira0*irc0;
        ct[(cb+1)*CTS + rb+0] = 1.0f - s01*ira0*irc1;
        ct[(cb+2)*CTS + rb+0] = 1.0f - s02*ira0*irc2;
        ct[(cb+0)*CTS + rb+1] = 1.0f - s10*ira1*irc0;
        ct[(cb+1)*CTS + rb+1] = 1.0f - s11*ira1*irc1;
        ct[(cb+2)*CTS + rb+1] = 1.0f - s12*ira1*irc2;
        ct[(cb+0)*CTS + rb+2] = 1.0f - s20*ira2*irc0;
        ct[(cb+1)*CTS + rb+2] = 1.0f - s21*ira2*irc1;
        ct[(cb+2)*CTS + rb+2] = 1.0f - s22*ira2*irc2;
    }
    LGKM0();   // order ds_write -> ds_read within this wave

    // ============ Phase B: DS-free Hungarian (JV SAP), one wave/batch ======
    const bool isCol = (lane < N);
    const int  jj    = isCol ? lane : 0;
    float cq[24];                         // lane j holds column j, rows 0..23
    {
        const float4* cp4 = (const float4*)&costT[wv][jj][0];
        #pragma unroll
        for (int r = 0; r < 6; ++r) {
            float4 q = cp4[r];
            cq[r*4+0] = q.x; cq[r*4+1] = q.y; cq[r*4+2] = q.z; cq[r*4+3] = q.w;
        }
    }

    // ---- column reduction warm start: v[j] = min_i C[i][j] ----
    float cm = cq[0]; int ri = 0;
    #pragma unroll
    for (int i = 1; i < N; ++i) { if (cq[i] < cm) { cm = cq[i]; ri = i; } }

    if (isCol) winner[wv][lane] = -1;
    LGKM0();
    if (isCol) winner[wv][ri] = lane;     // races resolve to one winner
    LGKM0();
    int p = -1;                           // row assigned to col `lane`
    if (isCol && winner[wv][ri] == lane) p = ri;
    const int widx = isCol ? lane : 0;
    unsigned long long mm = __ballot(isCol && winner[wv][widx] >= 0);
    unsigned freeRows = (~(unsigned)mm) & ((1u << N) - 1);

    float uu  = 0.0f;                     // lane r: row potential u[r]
    float v   = isCol ? cm : INFV;        // lane j: col potential v[j]
    int   way = -1;                       // lane j: parent col on path

    while (freeRows) {
        const int f = (int)__builtin_ctz(freeRows);
        freeRows &= freeRows - 1;

        float minv  = INFV;
        bool  used  = false;
        bool  inTree = false;
        int   s_j0 = -1;                  // virtual column
        int   s_i0 = f;
        float s_u0 = readlane_f(uu, f);
        int   j1   = 0;

        while (true) {
            inTree = inTree || (lane == s_i0);
            used   = used   || (lane == s_j0);

            float cij = csel(cq, s_i0);   // C[s_i0][lane] — uniform select
            float cur = cij - s_u0 - v;
            bool  act = isCol && !used;
            if (act && cur < minv) { minv = cur; way = s_j0; }
            float masked = act ? minv : INFV;

            // packed argmin via DPP: monotone uint key, low 6 bits = lane
            unsigned kmin = (unsigned)readlane_i(
                (int)wave_min32(packkey(masked, lane)), 31);
            j1 = (int)(kmin & 63u);

            float delta = readlane_f(masked, j1);
            int   i0n   = readlane_i(p, j1);
            float u0n   = readlane_f(uu, i0n & 31);   // safe dummy if i0n<0

            if (inTree) uu += delta;                  // rows in tree (incl f)
            if (used) v -= delta;
            else if (act) minv -= delta;

            if (i0n < 0) break;                       // free column reached
            s_j0 = j1; s_i0 = i0n; s_u0 = u0n;
        }

        // augment back to the virtual column
        int jcur = j1;
        while (true) {
            int wj   = readlane_i(way, jcur);
            int pnew = (wj < 0) ? f : readlane_i(p, wj);
            if (lane == jcur) p = pnew;
            if (wj < 0) break;
            jcur = wj;
        }
    }

    if (isCol) colw[wv][p] = lane;        // col_ind[row p] = col `lane`
    LGKM0();

    // ======= L-PROBE: 128 iterations of the exact SAP body shape ==========
    // Runs on junk state after the real solve; results sunk via asm so DCE
    // can't remove it (rule #17). Wall-time delta vs R0 = 128 * L_eff.
    {
        int   q_i0 = (int)(lane & 1);     // opaque-ish start
        float q_u0 = 0.0f;
        int   q_j0 = -1;
        float q_minv = INFV;
        float q_v  = v;
        float q_uu = uu;
        int   q_way = -1;
        bool  q_used = false, q_inTree = false;
        int   q_j1 = 0;
        #pragma unroll 1
        for (int k = 0; k < PROBE_ITERS; ++k) {
            q_inTree = q_inTree || (lane == q_i0);
            q_used   = q_used   || (lane == q_j0);

            float cij = csel(cq, q_i0);   // same uniform switch select
            float cur = cij - q_u0 - q_v;
            bool  act = isCol && !q_used;
            if (act && cur < q_minv) { q_minv = cur; q_way = q_j0; }
            float masked = act ? q_minv : INFV;

            unsigned kmin = (unsigned)readlane_i(
                (int)wave_min32(packkey(masked, lane)), 31);
            q_j1 = (int)(kmin & 63u);

            float delta = readlane_f(masked, q_j1);
            int   i0n   = readlane_i(p, q_j1);        // junk but opaque
            float u0n   = readlane_f(q_uu, i0n & 31);

            if (q_inTree) q_uu += delta;
            if (q_used) q_v -= delta;
            else if (act) q_minv -= delta;

            if (i0n < -1000000) break;                // never taken, opaque
            q_j0 = q_j1; q_i0 = i0n; q_u0 = u0n;
        }
        __asm__ volatile("" :: "v"(q_minv), "v"(q_v), "v"(q_uu),
                              "v"((float)q_way), "v"((float)q_j1));
    }

    // ============ Phase C: gather out[i][:] = slots[col[i]][:] =============
    const float4* sg4 = (const float4*)(slots + (size_t)bw * N * D);
    float4*       og4 = (float4*)(out + (size_t)bw * N * D);
    #pragma unroll
    for (int i = 0; i < N; ++i) {
        int c = colw[wv][i];
        og4[i * 64 + lane] = sg4[c * 64 + lane];
    }
}

extern "C" void kernel_launch(void* const* d_in, const int* in_sizes, int n_in,
                              void* d_out, int out_size, void* d_ws, size_t ws_size,
                              hipStream_t stream) {
    const float* slots = (const float*)d_in[0];
    const float* prev  = (const float*)d_in[1];
    float* out = (float*)d_out;
    int B = in_sizes[0] / (N * D);
    int grid = (B + NB - 1) / NB;
    hungarian_fused<<<grid, BLK, 0, stream>>>(slots, prev, out, B);
}

// Round 6
// 183.667 us; speedup vs baseline: 1.3019x; 1.3019x over previous
//
#include <hip/hip_runtime.h>
#include <math.h>

#define N    24
#define D    256
#define BLK  256
#define NB   4            // batches per block = waves per block
#define CTS  33           // costT row stride: 33 % 32 == 1 -> conflict-free column reads
#define INFV 1e9f

__device__ __forceinline__ int readlane_i(int x, int l) {
    return __builtin_amdgcn_readlane(x, l);
}
__device__ __forceinline__ float readlane_f(float x, int l) {
    return __uint_as_float((unsigned)__builtin_amdgcn_readlane((int)__float_as_uint(x), l));
}

// unsigned-min reduce over lanes 0..31 (lanes 32..63 must hold large keys);
// result valid in lane 31. Pure DPP/VALU — no DS pipe.
__device__ __forceinline__ unsigned wave_min32(unsigned x) {
    unsigned t;
    t = (unsigned)__builtin_amdgcn_update_dpp((int)x, (int)x, 0xB1,  0xF, 0xF, false); x = t < x ? t : x; // quad_perm [1,0,3,2]
    t = (unsigned)__builtin_amdgcn_update_dpp((int)x, (int)x, 0x4E,  0xF, 0xF, false); x = t < x ? t : x; // quad_perm [2,3,0,1]
    t = (unsigned)__builtin_amdgcn_update_dpp((int)x, (int)x, 0x114, 0xF, 0xF, false); x = t < x ? t : x; // row_shr:4
    t = (unsigned)__builtin_amdgcn_update_dpp((int)x, (int)x, 0x118, 0xF, 0xF, false); x = t < x ? t : x; // row_shr:8  -> lane15 = row min
    t = (unsigned)__builtin_amdgcn_update_dpp((int)x, (int)x, 0x142, 0xF, 0xF, false); x = t < x ? t : x; // row_bcast:15 -> lane31 = min(0..31)
    return x;
}

__device__ __forceinline__ unsigned packkey(float x, int lane) {
    unsigned key = __float_as_uint(x);
    key ^= (unsigned)((int)key >> 31) | 0x80000000u;
    return (key & 0xFFFFFFC0u) | (unsigned)lane;
}

#define DOT4(a, b) ((a).x*(b).x + (a).y*(b).y + (a).z*(b).z + (a).w*(b).w)
#define LGKM0() __asm__ volatile("s_waitcnt lgkmcnt(0)" ::: "memory")

__global__ __launch_bounds__(BLK) void hungarian_fused(
    const float* __restrict__ slots,
    const float* __restrict__ prev,
    float* __restrict__ out, int B)
{
    __shared__ float costT[NB][N][CTS];               // [wave][col][row]
    __shared__ int winner[NB][N];                     // col claiming row r
    __shared__ int colw[NB][N];                       // col_ind[row]

    const int tid  = threadIdx.x;
    const int lane = tid & 63;
    const int wv   = tid >> 6;
    const int bw   = blockIdx.x * NB + wv;
    if (bw >= B) return;

    // ============ Phase A: per-wave cost GEMM straight from global =========
    const int rg = lane >> 3;       // prev rows 3rg..3rg+2
    const int cg = lane & 7;        // cur  rows 3cg..3cg+2
    const float4* pA = (const float4*)(prev  + (size_t)bw * N * D) + rg * 3 * (D / 4);
    const float4* pC = (const float4*)(slots + (size_t)bw * N * D) + cg * 3 * (D / 4);

    float s00=0,s01=0,s02=0,s10=0,s11=0,s12=0,s20=0,s21=0,s22=0;
    float pa0=0,pa1=0,pa2=0,pc0=0,pc1=0,pc2=0;
    #pragma unroll 2
    for (int k = 0; k < 64; ++k) {
        float4 a0 = pA[k], a1 = pA[64+k], a2 = pA[128+k];
        float4 b0 = pC[k], b1 = pC[64+k], b2 = pC[128+k];
        s00 += DOT4(a0,b0); s01 += DOT4(a0,b1); s02 += DOT4(a0,b2);
        s10 += DOT4(a1,b0); s11 += DOT4(a1,b1); s12 += DOT4(a1,b2);
        s20 += DOT4(a2,b0); s21 += DOT4(a2,b1); s22 += DOT4(a2,b2);
        pa0 += DOT4(a0,a0); pa1 += DOT4(a1,a1); pa2 += DOT4(a2,a2);
        pc0 += DOT4(b0,b0); pc1 += DOT4(b1,b1); pc2 += DOT4(b2,b2);
    }
    float ira0 = 1.0f / fmaxf(sqrtf(pa0), 1e-12f);
    float ira1 = 1.0f / fmaxf(sqrtf(pa1), 1e-12f);
    float ira2 = 1.0f / fmaxf(sqrtf(pa2), 1e-12f);
    float irc0 = 1.0f / fmaxf(sqrtf(pc0), 1e-12f);
    float irc1 = 1.0f / fmaxf(sqrtf(pc1), 1e-12f);
    float irc2 = 1.0f / fmaxf(sqrtf(pc2), 1e-12f);

    {   // costT[col][row] = 1 - <prev_row, cur_col> * ira * irc
        float* ct = &costT[wv][0][0];
        const int cb = cg * 3, rb = rg * 3;
        ct[(cb+0)*CTS + rb+0] = 1.0f - s00*ira0*irc0;
        ct[(cb+1)*CTS + rb+0] = 1.0f - s01*ira0*irc1;
        ct[(cb+2)*CTS + rb+0] = 1.0f - s02*ira0*irc2;
        ct[(cb+0)*CTS + rb+1] = 1.0f - s10*ira1*irc0;
        ct[(cb+1)*CTS + rb+1] = 1.0f - s11*ira1*irc1;
        ct[(cb+2)*CTS + rb+1] = 1.0f - s12*ira1*irc2;
        ct[(cb+0)*CTS + rb+2] = 1.0f - s20*ira2*irc0;
        ct[(cb+1)*CTS + rb+2] = 1.0f - s21*ira2*irc1;
        ct[(cb+2)*CTS + rb+2] = 1.0f - s22*ira2*irc2;
    }
    LGKM0();   // order ds_write -> ds_read within this wave

    // ============ Phase B: Hungarian (JV SAP), one wave/batch ==============
    // Lane j owns column j. Fully predicated loop body: no divergent ifs,
    // no exec-mask save/restore, independent post-argmin readlanes.
    const bool isCol = (lane < N);
    const int  cl    = isCol ? lane : (N - 1);   // lanes>=24: broadcast col 23
    const float* __restrict__ ctcol = &costT[wv][cl][0];  // stride 33: conflict-free

    // ---- column reduction warm start: v[j] = min_i C[i][j] ----
    float cq[N];
    #pragma unroll
    for (int i = 0; i < N; ++i) cq[i] = ctcol[i];
    float cm = cq[0]; int ri = 0;
    #pragma unroll
    for (int i = 1; i < N; ++i) { if (cq[i] < cm) { cm = cq[i]; ri = i; } }

    if (isCol) winner[wv][lane] = -1;
    LGKM0();
    if (isCol) winner[wv][ri] = lane;     // races resolve to one winner
    LGKM0();
    int p = -1;                           // row assigned to col `lane`
    if (isCol && winner[wv][ri] == lane) p = ri;
    const int widx = isCol ? lane : 0;
    unsigned long long mm = __ballot(isCol && winner[wv][widx] >= 0);
    unsigned freeRows = (~(unsigned)mm) & ((1u << N) - 1);

    float uu  = 0.0f;                     // lane r: row potential u[r]
    float pu  = 0.0f;                     // lane j: u[p[j]] shadow (exact; u==0 now)
    float v   = isCol ? cm : INFV;        // lane j: col potential v[j]
    int   way = -1;                       // lane j: parent col on path

    while (freeRows) {
        const int f = (int)__builtin_ctz(freeRows);
        freeRows &= freeRows - 1;

        float minv  = INFV;
        bool  used  = !isCol;             // lanes>=24 permanently excluded
        bool  inTree = false;
        int   s_j0 = -1;                  // virtual column
        int   s_i0 = f;
        float s_u0 = readlane_f(uu, f);
        int   j1   = 0;

        while (true) {
            inTree = inTree || (lane == s_i0);

            // C[s_i0][lane]: branch-free conflict-free LDS read (early issue)
            float cij = ctcol[s_i0];
            float cur = (cij - s_u0) - v;             // exact old association

            bool imp = (!used) && (cur < minv);
            minv = imp ? cur : minv;                  // used lanes frozen at INFV
            way  = imp ? s_j0 : way;

            // packed argmin via DPP: monotone uint key, low 6 bits = lane
            unsigned kmin = (unsigned)readlane_i(
                (int)wave_min32(packkey(minv, lane)), 31);
            j1 = (int)(kmin & 63u);

            // three INDEPENDENT readlanes off j1 (pu shadow kills the
            // old p[j1] -> uu[p[j1]] serialized double-hop)
            float delta = readlane_f(minv, j1);
            int   i0n   = readlane_i(p, j1);
            float u0n   = readlane_f(pu, j1);

            // dual updates — predicated, same used/inTree sets as before
            uu   = inTree ? uu + delta : uu;
            v    = used   ? v - delta  : v;
            pu   = used   ? pu + delta : pu;          // mirrors u[p[j]]
            minv = used   ? minv       : minv - delta;

            // col j1 joins the used set for subsequent iterations
            bool sel = (lane == j1);
            minv = sel ? INFV : minv;
            used = used || sel;

            if (i0n < 0) break;                       // free column reached
            s_j0 = j1; s_i0 = i0n; s_u0 = u0n;
        }

        // augment back to the virtual column; resync pu = u[p[j]] on the path
        int jcur = j1;
        while (true) {
            int   wj   = readlane_i(way, jcur);
            int   pnew = (wj < 0) ? f : readlane_i(p, wj);
            float pun  = readlane_f(uu, pnew);
            if (lane == jcur) { p = pnew; pu = pun; }
            if (wj < 0) break;
            jcur = wj;
        }
    }

    if (isCol) colw[wv][p] = lane;        // col_ind[row p] = col `lane`
    LGKM0();

    // ============ Phase C: gather out[i][:] = slots[col[i]][:] =============
    const float4* sg4 = (const float4*)(slots + (size_t)bw * N * D);
    float4*       og4 = (float4*)(out + (size_t)bw * N * D);
    #pragma unroll
    for (int i = 0; i < N; ++i) {
        int c = colw[wv][i];
        og4[i * 64 + lane] = sg4[c * 64 + lane];
    }
}

extern "C" void kernel_launch(void* const* d_in, const int* in_sizes, int n_in,
                              void* d_out, int out_size, void* d_ws, size_t ws_size,
                              hipStream_t stream) {
    const float* slots = (const float*)d_in[0];
    const float* prev  = (const float*)d_in[1];
    float* out = (float*)d_out;
    int B = in_sizes[0] / (N * D);
    int grid = (B + NB - 1) / NB;
    hungarian_fused<<<grid, BLK, 0, stream>>>(slots, prev, out, B);
}